// Round 10
// baseline (377.525 us; speedup 1.0000x reference)
//
#include <hip/hip_runtime.h>
#include <hip/hip_bf16.h>

#define NN 50000
#define NE 800000
#define HCn 256
#define LATn 64

typedef short bf16x4 __attribute__((ext_vector_type(4)));
typedef short bf16x8 __attribute__((ext_vector_type(8)));
typedef float f32x4 __attribute__((ext_vector_type(4)));

__device__ __forceinline__ short f2b(float f) {
    __hip_bfloat16 h = __float2bfloat16(f);   // RNE
    return __builtin_bit_cast(short, h);
}
__device__ __forceinline__ float b2f(short s) {
    return __bfloat162float(__builtin_bit_cast(__hip_bfloat16, s));
}

// single-instruction lane swizzle (BitMode xor; works within 32-lane halves)
#define SWZF(v, pat) __builtin_bit_cast(float, __builtin_amdgcn_ds_swizzle(__builtin_bit_cast(int, v), pat))

// DPP add: s += lane-permuted s (within 16-lane DPP row; VALU pipe, no DS).
// CTRL must be a compile-time constant -> template parameter.
template<int CTRL>
__device__ __forceinline__ float dpp_add(float s) {
    int si = __builtin_bit_cast(int, s);
    int r  = __builtin_amdgcn_update_dpp(si, si, CTRL, 0xF, 0xF, false);
    return s + __builtin_bit_cast(float, r);
}
// full 16-lane sum, result in all lanes: xor1, xor2 (quad_perm), then cyclic ror4, ror8
__device__ __forceinline__ float red16(float s) {
    s = dpp_add<0xB1>(s);    // quad_perm [1,0,3,2]  (xor 1)
    s = dpp_add<0x4E>(s);    // quad_perm [2,3,0,1]  (xor 2)
    s = dpp_add<0x124>(s);   // row_ror:4
    s = dpp_add<0x128>(s);   // row_ror:8
    return s;
}

#define C04L2E 0.5770780163555854f   // 0.4 * log2(e)
#define C06L2E 0.8656170245333781f   // 0.6 * log2(e)
#define DEFER_THR 8.0f               // defer-max threshold (log2 units)

// ---------------- CSR build ----------------
__global__ void hist_kernel(const int* __restrict__ dst, int* __restrict__ counts) {
    int e = blockIdx.x * 256 + threadIdx.x;
    if (e < NE) atomicAdd(&counts[dst[e]], 1);
}

__global__ __launch_bounds__(1024) void scan1_kernel(int* __restrict__ counts,
                                                     int* __restrict__ blocksum) {
    const int g = blockIdx.x * 1024 + threadIdx.x;
    const int lane = threadIdx.x & 63;
    const int wv = threadIdx.x >> 6;            // 0..15
    int v = (g < NN) ? counts[g] : 0;
    int s = v;
#pragma unroll
    for (int d = 1; d < 64; d <<= 1) {
        int t = __shfl_up(s, d, 64);
        if (lane >= d) s += t;
    }
    __shared__ int wsum[16];
    if (lane == 63) wsum[wv] = s;
    __syncthreads();
    if (threadIdx.x == 0) {
        int run = 0;
#pragma unroll
        for (int q = 0; q < 16; ++q) { int t = wsum[q]; wsum[q] = run; run += t; }
        blocksum[blockIdx.x] = run;
    }
    __syncthreads();
    int excl = s - v + wsum[wv];
    if (g < NN) counts[g] = excl;
}

__global__ void scan2_kernel(int* __restrict__ blocksum, int* __restrict__ offsets, int nblk) {
    const int lane = threadIdx.x;               // 64 threads
    int v = (lane < nblk) ? blocksum[lane] : 0;
    int s = v;
#pragma unroll
    for (int d = 1; d < 64; d <<= 1) {
        int t = __shfl_up(s, d, 64);
        if (lane >= d) s += t;
    }
    if (lane < nblk) blocksum[lane] = s - v;    // exclusive
    if (lane == 0) offsets[NN] = NE;
}

__global__ __launch_bounds__(1024) void scan3_kernel(const int* __restrict__ counts,
                                                     const int* __restrict__ blocksum,
                                                     int* __restrict__ offsets,
                                                     int* __restrict__ cursor) {
    const int g = blockIdx.x * 1024 + threadIdx.x;
    if (g < NN) {
        int v = counts[g] + blocksum[blockIdx.x];
        offsets[g] = v;
        cursor[g]  = v;
    }
}

__global__ void scatter_kernel(const int* __restrict__ src, const int* __restrict__ dst,
                               int* __restrict__ cursor, int* __restrict__ csr_src) {
    int e = blockIdx.x * 256 + threadIdx.x;
    if (e < NE) {
        int p = atomicAdd(&cursor[dst[e]], 1);
        csr_src[p] = src[e];
    }
}

// ---------------- pack weights to bf16, TRANSPOSED: Wbt[n][k] = W[k][n] ----------------
__global__ void pack_w_kernel(const float* __restrict__ Wl1, const float* __restrict__ Wr1,
                              const float* __restrict__ Wl2, const float* __restrict__ Wr2,
                              const float* __restrict__ Wmu, const float* __restrict__ Wlv,
                              const float* __restrict__ bmu, const float* __restrict__ blv,
                              short* __restrict__ Wb1t, short* __restrict__ Wb2t,
                              short* __restrict__ Wb3t, float* __restrict__ bias3) {
    int i = blockIdx.x * 256 + threadIdx.x;
    const int S1 = 512 * 256, S2 = 2 * S1, S3 = S2 + 128 * 256;
    if (i < S1) {
        int c = i >> 8, k = i & 255;
        float v = (c < 256) ? Wl1[k * 256 + c] : Wr1[k * 256 + (c - 256)];
        Wb1t[i] = f2b(v);
    } else if (i < S2) {
        int j = i - S1; int c = j >> 8, k = j & 255;
        float v = (c < 256) ? Wl2[k * 256 + c] : Wr2[k * 256 + (c - 256)];
        Wb2t[j] = f2b(v);
    } else if (i < S3) {
        int j = i - S2; int c = j >> 8, k = j & 255;
        float v = (c < 64) ? Wmu[k * 64 + c] : Wlv[k * 64 + (c - 64)];
        Wb3t[j] = f2b(v);
    } else if (i < S3 + 128) {
        int c = i - S3;
        bias3[c] = (c < 64) ? bmu[c] : blv[c - 64];
    }
}

// ---------------- GEMM: out[M,Nc] = A[M,256] @ W[256,Nc], Wbt[Nc,256] transposed ----------------
// 128x128 tile, 4 waves; B panel staged once in LDS with XOR swizzle; A frags direct from global.
template<int A_F32, int OUT_MODE>   // OUT_MODE 0: bf16 out stride Nc | 1: f32 out split 64|64 + bias
__global__ __launch_bounds__(256) void gemm_k(
    const void* __restrict__ Ap, const short* __restrict__ Wbt,
    void* __restrict__ outp, const float* __restrict__ bias, int Nc)
{
    __shared__ short Bs[128 * 256];   // 64 KB, XOR-swizzled chunks (16B granule)
    const int t = threadIdx.x;
    const int w = t >> 6, lane = t & 63;
    const int row0 = blockIdx.x * 128, col0 = blockIdx.y * 128;

    // stage: Bs[row][chunk^(row&7)] = Wbt[col0+row][chunk]  (chunk = 8 shorts = 16B)
    {
        const int sn = t >> 1;            // 0..127
        const int half = t & 1;
        const short* wp = Wbt + (long)(col0 + sn) * 256 + half * 128;
        short* bp = &Bs[sn * 256];
        const int sx = sn & 7;
#pragma unroll
        for (int r = 0; r < 16; ++r) {
            bf16x8 v = *reinterpret_cast<const bf16x8*>(wp + r * 8);
            int c = half * 16 + r;
            *reinterpret_cast<bf16x8*>(bp + ((c ^ sx) * 8)) = v;
        }
    }
    __syncthreads();

    f32x4 acc[2][8];
#pragma unroll
    for (int a = 0; a < 2; ++a)
#pragma unroll
        for (int b = 0; b < 8; ++b) acc[a][b] = (f32x4){0.f, 0.f, 0.f, 0.f};

    const int arow = lane & 15, kq = lane >> 4;
    const int xorc = arow & 7;
    int r0 = row0 + w * 32 + arow;      if (r0 > NN - 1) r0 = NN - 1;
    int r1 = row0 + w * 32 + 16 + arow; if (r1 > NN - 1) r1 = NN - 1;

#pragma unroll
    for (int k0 = 0; k0 < 256; k0 += 32) {
        bf16x8 a0, a1;
        if (A_F32) {
            const float* A = (const float*)Ap;
            const f32x4* q0 = reinterpret_cast<const f32x4*>(A + (long)r0 * 256 + kq * 8 + k0);
            const f32x4* q1 = reinterpret_cast<const f32x4*>(A + (long)r1 * 256 + kq * 8 + k0);
            f32x4 u0 = q0[0], u1 = q0[1], v0 = q1[0], v1 = q1[1];
#pragma unroll
            for (int j = 0; j < 4; ++j) {
                a0[j] = f2b(u0[j]); a0[4 + j] = f2b(u1[j]);
                a1[j] = f2b(v0[j]); a1[4 + j] = f2b(v1[j]);
            }
        } else {
            const short* A = (const short*)Ap;
            a0 = *reinterpret_cast<const bf16x8*>(A + (long)r0 * 256 + kq * 8 + k0);
            a1 = *reinterpret_cast<const bf16x8*>(A + (long)r1 * 256 + kq * 8 + k0);
        }
        const int chunk = ((k0 >> 3) + kq) ^ xorc;
        const short* bsp = &Bs[arow * 256 + chunk * 8];
#pragma unroll
        for (int nt = 0; nt < 8; ++nt) {
            bf16x8 b = *reinterpret_cast<const bf16x8*>(bsp + nt * 4096);  // +16 rows
            acc[0][nt] = __builtin_amdgcn_mfma_f32_16x16x32_bf16(a0, b, acc[0][nt], 0, 0, 0);
            acc[1][nt] = __builtin_amdgcn_mfma_f32_16x16x32_bf16(a1, b, acc[1][nt], 0, 0, 0);
        }
    }

    // epilogue: C/D layout col = lane&15, row = (lane>>4)*4 + r
#pragma unroll
    for (int rb = 0; rb < 2; ++rb)
#pragma unroll
        for (int nt = 0; nt < 8; ++nt) {
            int gcol = col0 + nt * 16 + arow;
#pragma unroll
            for (int r = 0; r < 4; ++r) {
                int grow = row0 + w * 32 + rb * 16 + kq * 4 + r;
                if (grow < NN) {
                    float v = acc[rb][nt][r];
                    if (OUT_MODE == 0) {
                        ((short*)outp)[(long)grow * Nc + gcol] = f2b(v);
                    } else {
                        v += bias[gcol];
                        float* o = (float*)outp;
                        if (gcol < 64) o[(long)grow * 64 + gcol] = v;
                        else           o[(long)NN * 64 + (long)grow * 64 + (gcol - 64)] = v;
                    }
                }
            }
        }
}

// ---------------- att_pre: a[i][h] = 0.6*log2e * sum_c att[h][c]*xl[i][c] ----------------
__global__ __launch_bounds__(256) void att_pre_kernel(
    const short* __restrict__ xlr, const float* __restrict__ att, float* __restrict__ a)
{
    const int i = blockIdx.x * 4 + (threadIdx.x >> 6);
    const int lane = threadIdx.x & 63;
    const int c4 = (lane >> 4) * 64 + (lane & 15) * 4;
    f32x4 attv = *reinterpret_cast<const f32x4*>(att + c4);
    bf16x4 v = *reinterpret_cast<const bf16x4*>(xlr + (long)i * 512 + c4);
    float s = 0.f;
#pragma unroll
    for (int k = 0; k < 4; ++k) s = fmaf(b2f(v[k]), attv[k], s);
    s = red16(s);
    if ((lane & 15) == 0) a[i * 4 + (lane >> 4)] = s * C06L2E;
}

// ---------------- fused GATv2 v2 + index prefetch + DPP reduce ----------------
// score (log2 domain, dst-constant term dropped): s = a[j][h] + sum_c (0.4*log2e*att_c)*|xl_jc+xr_ic|
__device__ __forceinline__ void edge_abs_score(const short* __restrict__ xlr, int j, int c4,
                                               const float* xr, const f32x4& attv04,
                                               float* xf, float& s) {
    bf16x4 v = *reinterpret_cast<const bf16x4*>(xlr + (long)j * 512 + c4);
    s = 0.f;
#pragma unroll
    for (int k = 0; k < 4; ++k) {
        xf[k] = b2f(v[k]);
        float vv = xf[k] + xr[k];
        s = fmaf(attv04[k], fabsf(vv), s);   // abs = free input modifier
    }
    s = red16(s);                            // 4 DPP VALU ops, no DS
}

__global__ __launch_bounds__(256) void gat_node_kernel(
    const short* __restrict__ xlr, const float* __restrict__ aarr,
    const int* __restrict__ offsets, const int* __restrict__ csr_src,
    const float* __restrict__ att, const float* __restrict__ bias,
    const float* __restrict__ ln_g, const float* __restrict__ ln_b,
    short* __restrict__ hout)
{
    const int i = blockIdx.x * 4 + (threadIdx.x >> 6);
    const int lane = threadIdx.x & 63;
    const int h  = lane >> 4;
    const int c4 = h * 64 + (lane & 15) * 4;   // head*64 + 4 channels

    f32x4 attv04 = *reinterpret_cast<const f32x4*>(att + c4);
#pragma unroll
    for (int k = 0; k < 4; ++k) attv04[k] *= C04L2E;

    float xr[4];
    {
        bf16x4 v = *reinterpret_cast<const bf16x4*>(xlr + (long)i * 512 + 256 + c4);
#pragma unroll
        for (int k = 0; k < 4; ++k) xr[k] = b2f(v[k]);
    }

    const int p0 = offsets[i], p1 = offsets[i + 1];

    // prefetch first pass's indices (clamped, branchless)
    int pp = p0 + (lane & 3);
    int jl = csr_src[pp < NE ? pp : NE - 1];

    float m, l;
    float acc[4];
    // self loop first
    {
        float aj = aarr[i * 4 + h];
        float xf[4], s;
        edge_abs_score(xlr, i, c4, xr, attv04, xf, s);
        m = s + aj; l = 1.f;
#pragma unroll
        for (int k = 0; k < 4; ++k) acc[k] = xf[k];
    }

    int p = p0;
    for (; p + 4 <= p1; p += 4) {
        int j0 = __builtin_amdgcn_readlane(jl, 0);
        int j1 = __builtin_amdgcn_readlane(jl, 1);
        int j2 = __builtin_amdgcn_readlane(jl, 2);
        int j3 = __builtin_amdgcn_readlane(jl, 3);
        // prefetch next pass (or tail) indices while this pass computes
        int pn = p + 4 + (lane & 3);
        jl = csr_src[pn < p1 ? pn : (p1 > 0 ? p1 - 1 : 0)];
        float a0 = aarr[j0 * 4 + h], a1 = aarr[j1 * 4 + h];
        float a2 = aarr[j2 * 4 + h], a3 = aarr[j3 * 4 + h];
        float x0[4], x1[4], x2[4], x3[4], s0, s1, s2, s3;
        edge_abs_score(xlr, j0, c4, xr, attv04, x0, s0);
        edge_abs_score(xlr, j1, c4, xr, attv04, x1, s1);
        edge_abs_score(xlr, j2, c4, xr, attv04, x2, s2);
        edge_abs_score(xlr, j3, c4, xr, attv04, x3, s3);
        s0 += a0; s1 += a1; s2 += a2; s3 += a3;
        float sm = fmaxf(fmaxf(s0, s1), fmaxf(s2, s3));
        if (__all(sm <= m + DEFER_THR)) {
            float e0 = __builtin_amdgcn_exp2f(s0 - m);
            float e1 = __builtin_amdgcn_exp2f(s1 - m);
            float e2 = __builtin_amdgcn_exp2f(s2 - m);
            float e3 = __builtin_amdgcn_exp2f(s3 - m);
            l += (e0 + e1) + (e2 + e3);
#pragma unroll
            for (int k = 0; k < 4; ++k)
                acc[k] = fmaf(e0, x0[k], fmaf(e1, x1[k], fmaf(e2, x2[k], fmaf(e3, x3[k], acc[k]))));
        } else {
            float mn = fmaxf(m, sm);
            float corr = __builtin_amdgcn_exp2f(m - mn);
            float e0 = __builtin_amdgcn_exp2f(s0 - mn);
            float e1 = __builtin_amdgcn_exp2f(s1 - mn);
            float e2 = __builtin_amdgcn_exp2f(s2 - mn);
            float e3 = __builtin_amdgcn_exp2f(s3 - mn);
            l = fmaf(l, corr, (e0 + e1) + (e2 + e3));
#pragma unroll
            for (int k = 0; k < 4; ++k)
                acc[k] = fmaf(acc[k], corr,
                         fmaf(e0, x0[k], fmaf(e1, x1[k], fmaf(e2, x2[k], e3 * x3[k]))));
            m = mn;
        }
    }
    // tail 0..3 edges: indices already resident in jl (lanes 0..rem-1)
    int rem = p1 - p;
    for (int tq = 0; tq < rem; ++tq) {
        int j = __builtin_amdgcn_readlane(jl, tq);
        float aj = aarr[j * 4 + h];
        float xa[4], sa;
        edge_abs_score(xlr, j, c4, xr, attv04, xa, sa);
        sa += aj;
        if (__all(sa <= m + DEFER_THR)) {
            float ex = __builtin_amdgcn_exp2f(sa - m);
            l += ex;
#pragma unroll
            for (int k = 0; k < 4; ++k) acc[k] = fmaf(ex, xa[k], acc[k]);
        } else {
            float mn = fmaxf(m, sa);
            float corr = __builtin_amdgcn_exp2f(m - mn);
            float ex = __builtin_amdgcn_exp2f(sa - mn);
            l = fmaf(l, corr, ex);
#pragma unroll
            for (int k = 0; k < 4; ++k) acc[k] = fmaf(acc[k], corr, ex * xa[k]);
            m = mn;
        }
    }

    float inv = 1.f / l;
    f32x4 bv = *reinterpret_cast<const f32x4*>(bias + c4);
    float out[4], s1 = 0.f, s2 = 0.f;
#pragma unroll
    for (int k = 0; k < 4; ++k) {
        out[k] = acc[k] * inv + bv[k];
        s1 += out[k];
        s2 += out[k] * out[k];
    }
    // LN over 256 channels: DPP within 16, swizzle xor16, shfl xor32
    s1 = red16(s1); s2 = red16(s2);
    s1 += SWZF(s1, 0x401F); s2 += SWZF(s2, 0x401F);
    s1 += __shfl_xor(s1, 32, 64);
    s2 += __shfl_xor(s2, 32, 64);
    float mu  = s1 * (1.f / 256.f);
    float var = s2 * (1.f / 256.f) - mu * mu;
    float rs  = rsqrtf(var + 1e-5f);
    f32x4 gv  = *reinterpret_cast<const f32x4*>(ln_g + c4);
    f32x4 bbv = *reinterpret_cast<const f32x4*>(ln_b + c4);
    bf16x4 o;
#pragma unroll
    for (int k = 0; k < 4; ++k) {
        float y = (out[k] - mu) * rs * gv[k] + bbv[k];
        y = y > 0.f ? y : expm1f(y);                    // ELU
        o[k] = f2b(y);
    }
    *reinterpret_cast<bf16x4*>(hout + (long)i * 256 + c4) = o;
}

// ---------------- launch ----------------
extern "C" void kernel_launch(void* const* d_in, const int* in_sizes, int n_in,
                              void* d_out, int out_size, void* d_ws, size_t ws_size,
                              hipStream_t stream) {
    const float* x    = (const float*)d_in[0];
    const int*   ei   = (const int*)d_in[1];
    const float* Wl1  = (const float*)d_in[2];
    const float* Wr1  = (const float*)d_in[3];
    const float* att1 = (const float*)d_in[4];
    const float* b1   = (const float*)d_in[5];
    const float* ln1g = (const float*)d_in[6];
    const float* ln1b = (const float*)d_in[7];
    const float* Wl2  = (const float*)d_in[8];
    const float* Wr2  = (const float*)d_in[9];
    const float* att2 = (const float*)d_in[10];
    const float* b2   = (const float*)d_in[11];
    const float* ln2g = (const float*)d_in[12];
    const float* ln2b = (const float*)d_in[13];
    const float* Wmu  = (const float*)d_in[14];
    const float* bmu  = (const float*)d_in[15];
    const float* Wlv  = (const float*)d_in[16];
    const float* blv  = (const float*)d_in[17];

    // workspace layout
    short* bufXL = (short*)d_ws;                       // [N,512] bf16 (xl|xr)
    short* bufH  = bufXL + (long)NN * 512;             // [N,256] bf16 (h)
    short* Wb1t  = bufH + (long)NN * 256;              // 512*256
    short* Wb2t  = Wb1t + 512 * 256;
    short* Wb3t  = Wb2t + 512 * 256;                   // 128*256
    float* bias3 = (float*)(Wb3t + 128 * 256);         // 128
    int* counts  = (int*)(bias3 + 128);
    int* offsets = counts + NN;                        // N+1
    int* cursor  = offsets + NN + 1;
    int* csr_src = cursor + NN;                        // E
    int* blocksum = csr_src + NE;                      // 64
    float* a_arr = (float*)(blocksum + 64);            // [N,4]

    const int* src = ei;
    const int* dst = ei + NE;

    const int NBLK = (NN + 1023) / 1024;               // 49

    // CSR by dst (parallel scan)
    hipMemsetAsync(counts, 0, NN * sizeof(int), stream);
    hist_kernel<<<(NE + 255) / 256, 256, 0, stream>>>(dst, counts);
    scan1_kernel<<<NBLK, 1024, 0, stream>>>(counts, blocksum);
    scan2_kernel<<<1, 64, 0, stream>>>(blocksum, offsets, NBLK);
    scan3_kernel<<<NBLK, 1024, 0, stream>>>(counts, blocksum, offsets, cursor);
    scatter_kernel<<<(NE + 255) / 256, 256, 0, stream>>>(src, dst, cursor, csr_src);

    // pack transposed weights
    pack_w_kernel<<<1153, 256, 0, stream>>>(Wl1, Wr1, Wl2, Wr2, Wmu, Wlv, bmu, blv,
                                            Wb1t, Wb2t, Wb3t, bias3);

    const int GM = (NN + 127) / 128;   // 391
    dim3 g1(GM, 4);                    // Nc=512, 128-col tiles
    dim3 g3(GM, 1);                    // Nc=128

    // layer 1 (A = x in f32, converted in-register)
    gemm_k<1, 0><<<g1, 256, 0, stream>>>(x, Wb1t, bufXL, nullptr, 512);
    att_pre_kernel<<<NN / 4, 256, 0, stream>>>(bufXL, att1, a_arr);
    gat_node_kernel<<<NN / 4, 256, 0, stream>>>(bufXL, a_arr, offsets, csr_src,
                                                att1, b1, ln1g, ln1b, bufH);
    // layer 2
    gemm_k<0, 0><<<g1, 256, 0, stream>>>(bufH, Wb2t, bufXL, nullptr, 512);
    att_pre_kernel<<<NN / 4, 256, 0, stream>>>(bufXL, att2, a_arr);
    gat_node_kernel<<<NN / 4, 256, 0, stream>>>(bufXL, a_arr, offsets, csr_src,
                                                att2, b2, ln2g, ln2b, bufH);
    // heads: [mu|logvar]
    gemm_k<0, 1><<<g3, 256, 0, stream>>>(bufH, Wb3t, d_out, bias3, 128);
}

// Round 11
// 374.025 us; speedup vs baseline: 1.0094x; 1.0094x over previous
//
#include <hip/hip_runtime.h>
#include <hip/hip_bf16.h>

#define NN 50000
#define NE 800000
#define HCn 256
#define LATn 64

typedef short bf16x4 __attribute__((ext_vector_type(4)));
typedef short bf16x8 __attribute__((ext_vector_type(8)));
typedef float f32x4 __attribute__((ext_vector_type(4)));

__device__ __forceinline__ short f2b(float f) {
    __hip_bfloat16 h = __float2bfloat16(f);   // RNE
    return __builtin_bit_cast(short, h);
}
__device__ __forceinline__ float b2f(short s) {
    return __bfloat162float(__builtin_bit_cast(__hip_bfloat16, s));
}

// single-instruction lane swizzle (BitMode xor; works within 32-lane halves).
// DS-pipe op: overlaps with other waves' VALU work (measured r8 vs r10: beats DPP).
#define SWZF(v, pat) __builtin_bit_cast(float, __builtin_amdgcn_ds_swizzle(__builtin_bit_cast(int, v), pat))

#define C04L2E 0.5770780163555854f   // 0.4 * log2(e)
#define C06L2E 0.8656170245333781f   // 0.6 * log2(e)
#define DEFER_THR 8.0f               // defer-max threshold (log2 units)

// ---------------- CSR build ----------------
__global__ void hist_kernel(const int* __restrict__ dst, int* __restrict__ counts) {
    int e = blockIdx.x * 256 + threadIdx.x;
    if (e < NE) atomicAdd(&counts[dst[e]], 1);
}

__global__ __launch_bounds__(1024) void scan1_kernel(int* __restrict__ counts,
                                                     int* __restrict__ blocksum) {
    const int g = blockIdx.x * 1024 + threadIdx.x;
    const int lane = threadIdx.x & 63;
    const int wv = threadIdx.x >> 6;            // 0..15
    int v = (g < NN) ? counts[g] : 0;
    int s = v;
#pragma unroll
    for (int d = 1; d < 64; d <<= 1) {
        int t = __shfl_up(s, d, 64);
        if (lane >= d) s += t;
    }
    __shared__ int wsum[16];
    if (lane == 63) wsum[wv] = s;
    __syncthreads();
    if (threadIdx.x == 0) {
        int run = 0;
#pragma unroll
        for (int q = 0; q < 16; ++q) { int t = wsum[q]; wsum[q] = run; run += t; }
        blocksum[blockIdx.x] = run;
    }
    __syncthreads();
    int excl = s - v + wsum[wv];
    if (g < NN) counts[g] = excl;
}

__global__ void scan2_kernel(int* __restrict__ blocksum, int* __restrict__ offsets, int nblk) {
    const int lane = threadIdx.x;               // 64 threads
    int v = (lane < nblk) ? blocksum[lane] : 0;
    int s = v;
#pragma unroll
    for (int d = 1; d < 64; d <<= 1) {
        int t = __shfl_up(s, d, 64);
        if (lane >= d) s += t;
    }
    if (lane < nblk) blocksum[lane] = s - v;    // exclusive
    if (lane == 0) offsets[NN] = NE;
}

__global__ __launch_bounds__(1024) void scan3_kernel(const int* __restrict__ counts,
                                                     const int* __restrict__ blocksum,
                                                     int* __restrict__ offsets,
                                                     int* __restrict__ cursor) {
    const int g = blockIdx.x * 1024 + threadIdx.x;
    if (g < NN) {
        int v = counts[g] + blocksum[blockIdx.x];
        offsets[g] = v;
        cursor[g]  = v;
    }
}

__global__ void scatter_kernel(const int* __restrict__ src, const int* __restrict__ dst,
                               int* __restrict__ cursor, int* __restrict__ csr_src) {
    int e = blockIdx.x * 256 + threadIdx.x;
    if (e < NE) {
        int p = atomicAdd(&cursor[dst[e]], 1);
        csr_src[p] = src[e];
    }
}

// ---------------- pack weights to bf16, TRANSPOSED: Wbt[n][k] = W[k][n] ----------------
__global__ void pack_w_kernel(const float* __restrict__ Wl1, const float* __restrict__ Wr1,
                              const float* __restrict__ Wl2, const float* __restrict__ Wr2,
                              const float* __restrict__ Wmu, const float* __restrict__ Wlv,
                              const float* __restrict__ bmu, const float* __restrict__ blv,
                              short* __restrict__ Wb1t, short* __restrict__ Wb2t,
                              short* __restrict__ Wb3t, float* __restrict__ bias3) {
    int i = blockIdx.x * 256 + threadIdx.x;
    const int S1 = 512 * 256, S2 = 2 * S1, S3 = S2 + 128 * 256;
    if (i < S1) {
        int c = i >> 8, k = i & 255;
        float v = (c < 256) ? Wl1[k * 256 + c] : Wr1[k * 256 + (c - 256)];
        Wb1t[i] = f2b(v);
    } else if (i < S2) {
        int j = i - S1; int c = j >> 8, k = j & 255;
        float v = (c < 256) ? Wl2[k * 256 + c] : Wr2[k * 256 + (c - 256)];
        Wb2t[j] = f2b(v);
    } else if (i < S3) {
        int j = i - S2; int c = j >> 8, k = j & 255;
        float v = (c < 64) ? Wmu[k * 64 + c] : Wlv[k * 64 + (c - 64)];
        Wb3t[j] = f2b(v);
    } else if (i < S3 + 128) {
        int c = i - S3;
        bias3[c] = (c < 64) ? bmu[c] : blv[c - 64];
    }
}

// ---------------- GEMM: out[M,Nc] = A[M,256] @ W[256,Nc], Wbt[Nc,256] transposed ----------------
// 128x128 tile, 4 waves; B panel staged once in LDS with XOR swizzle; A frags direct from global.
template<int A_F32, int OUT_MODE>   // OUT_MODE 0: bf16 out stride Nc | 1: f32 out split 64|64 + bias
__global__ __launch_bounds__(256) void gemm_k(
    const void* __restrict__ Ap, const short* __restrict__ Wbt,
    void* __restrict__ outp, const float* __restrict__ bias, int Nc)
{
    __shared__ short Bs[128 * 256];   // 64 KB, XOR-swizzled chunks (16B granule)
    const int t = threadIdx.x;
    const int w = t >> 6, lane = t & 63;
    const int row0 = blockIdx.x * 128, col0 = blockIdx.y * 128;

    // stage: Bs[row][chunk^(row&7)] = Wbt[col0+row][chunk]  (chunk = 8 shorts = 16B)
    {
        const int sn = t >> 1;            // 0..127
        const int half = t & 1;
        const short* wp = Wbt + (long)(col0 + sn) * 256 + half * 128;
        short* bp = &Bs[sn * 256];
        const int sx = sn & 7;
#pragma unroll
        for (int r = 0; r < 16; ++r) {
            bf16x8 v = *reinterpret_cast<const bf16x8*>(wp + r * 8);
            int c = half * 16 + r;
            *reinterpret_cast<bf16x8*>(bp + ((c ^ sx) * 8)) = v;
        }
    }
    __syncthreads();

    f32x4 acc[2][8];
#pragma unroll
    for (int a = 0; a < 2; ++a)
#pragma unroll
        for (int b = 0; b < 8; ++b) acc[a][b] = (f32x4){0.f, 0.f, 0.f, 0.f};

    const int arow = lane & 15, kq = lane >> 4;
    const int xorc = arow & 7;
    int r0 = row0 + w * 32 + arow;      if (r0 > NN - 1) r0 = NN - 1;
    int r1 = row0 + w * 32 + 16 + arow; if (r1 > NN - 1) r1 = NN - 1;

#pragma unroll
    for (int k0 = 0; k0 < 256; k0 += 32) {
        bf16x8 a0, a1;
        if (A_F32) {
            const float* A = (const float*)Ap;
            const f32x4* q0 = reinterpret_cast<const f32x4*>(A + (long)r0 * 256 + kq * 8 + k0);
            const f32x4* q1 = reinterpret_cast<const f32x4*>(A + (long)r1 * 256 + kq * 8 + k0);
            f32x4 u0 = q0[0], u1 = q0[1], v0 = q1[0], v1 = q1[1];
#pragma unroll
            for (int j = 0; j < 4; ++j) {
                a0[j] = f2b(u0[j]); a0[4 + j] = f2b(u1[j]);
                a1[j] = f2b(v0[j]); a1[4 + j] = f2b(v1[j]);
            }
        } else {
            const short* A = (const short*)Ap;
            a0 = *reinterpret_cast<const bf16x8*>(A + (long)r0 * 256 + kq * 8 + k0);
            a1 = *reinterpret_cast<const bf16x8*>(A + (long)r1 * 256 + kq * 8 + k0);
        }
        const int chunk = ((k0 >> 3) + kq) ^ xorc;
        const short* bsp = &Bs[arow * 256 + chunk * 8];
#pragma unroll
        for (int nt = 0; nt < 8; ++nt) {
            bf16x8 b = *reinterpret_cast<const bf16x8*>(bsp + nt * 4096);  // +16 rows
            acc[0][nt] = __builtin_amdgcn_mfma_f32_16x16x32_bf16(a0, b, acc[0][nt], 0, 0, 0);
            acc[1][nt] = __builtin_amdgcn_mfma_f32_16x16x32_bf16(a1, b, acc[1][nt], 0, 0, 0);
        }
    }

    // epilogue: C/D layout col = lane&15, row = (lane>>4)*4 + r
#pragma unroll
    for (int rb = 0; rb < 2; ++rb)
#pragma unroll
        for (int nt = 0; nt < 8; ++nt) {
            int gcol = col0 + nt * 16 + arow;
#pragma unroll
            for (int r = 0; r < 4; ++r) {
                int grow = row0 + w * 32 + rb * 16 + kq * 4 + r;
                if (grow < NN) {
                    float v = acc[rb][nt][r];
                    if (OUT_MODE == 0) {
                        ((short*)outp)[(long)grow * Nc + gcol] = f2b(v);
                    } else {
                        v += bias[gcol];
                        float* o = (float*)outp;
                        if (gcol < 64) o[(long)grow * 64 + gcol] = v;
                        else           o[(long)NN * 64 + (long)grow * 64 + (gcol - 64)] = v;
                    }
                }
            }
        }
}

// ---------------- att_pre: a[i][h] = 0.6*log2e * sum_c att[h][c]*xl[i][c] ----------------
__global__ __launch_bounds__(256) void att_pre_kernel(
    const short* __restrict__ xlr, const float* __restrict__ att, float* __restrict__ a)
{
    const int i = blockIdx.x * 4 + (threadIdx.x >> 6);
    const int lane = threadIdx.x & 63;
    const int c4 = (lane >> 4) * 64 + (lane & 15) * 4;
    f32x4 attv = *reinterpret_cast<const f32x4*>(att + c4);
    bf16x4 v = *reinterpret_cast<const bf16x4*>(xlr + (long)i * 512 + c4);
    float s = 0.f;
#pragma unroll
    for (int k = 0; k < 4; ++k) s = fmaf(b2f(v[k]), attv[k], s);
    s += SWZF(s, 0x041F);
    s += SWZF(s, 0x081F);
    s += SWZF(s, 0x101F);
    s += SWZF(s, 0x201F);
    if ((lane & 15) == 0) a[i * 4 + (lane >> 4)] = s * C06L2E;
}

// ---------------- fused GATv2 v2 + index prefetch (ds_swizzle reduce — measured fastest) ----------------
// score (log2 domain, dst-constant term dropped): s = a[j][h] + sum_c (0.4*log2e*att_c)*|xl_jc+xr_ic|
__device__ __forceinline__ void edge_abs_score(const short* __restrict__ xlr, int j, int c4,
                                               const float* xr, const f32x4& attv04,
                                               float* xf, float& s) {
    bf16x4 v = *reinterpret_cast<const bf16x4*>(xlr + (long)j * 512 + c4);
    s = 0.f;
#pragma unroll
    for (int k = 0; k < 4; ++k) {
        xf[k] = b2f(v[k]);
        float vv = xf[k] + xr[k];
        s = fmaf(attv04[k], fabsf(vv), s);   // abs = free input modifier
    }
    // 16-lane head-group reduce: xor 1,2,4,8 (DS pipe, overlaps other waves' VALU)
    s += SWZF(s, 0x041F);
    s += SWZF(s, 0x081F);
    s += SWZF(s, 0x101F);
    s += SWZF(s, 0x201F);
}

__global__ __launch_bounds__(256) void gat_node_kernel(
    const short* __restrict__ xlr, const float* __restrict__ aarr,
    const int* __restrict__ offsets, const int* __restrict__ csr_src,
    const float* __restrict__ att, const float* __restrict__ bias,
    const float* __restrict__ ln_g, const float* __restrict__ ln_b,
    short* __restrict__ hout)
{
    const int i = blockIdx.x * 4 + (threadIdx.x >> 6);
    const int lane = threadIdx.x & 63;
    const int h  = lane >> 4;
    const int c4 = h * 64 + (lane & 15) * 4;   // head*64 + 4 channels

    f32x4 attv04 = *reinterpret_cast<const f32x4*>(att + c4);
#pragma unroll
    for (int k = 0; k < 4; ++k) attv04[k] *= C04L2E;

    float xr[4];
    {
        bf16x4 v = *reinterpret_cast<const bf16x4*>(xlr + (long)i * 512 + 256 + c4);
#pragma unroll
        for (int k = 0; k < 4; ++k) xr[k] = b2f(v[k]);
    }

    const int p0 = offsets[i], p1 = offsets[i + 1];

    // prefetch first pass's indices (clamped, branchless)
    int pp = p0 + (lane & 3);
    int jl = csr_src[pp < NE ? pp : NE - 1];

    float m, l;
    float acc[4];
    // self loop first
    {
        float aj = aarr[i * 4 + h];
        float xf[4], s;
        edge_abs_score(xlr, i, c4, xr, attv04, xf, s);
        m = s + aj; l = 1.f;
#pragma unroll
        for (int k = 0; k < 4; ++k) acc[k] = xf[k];
    }

    int p = p0;
    for (; p + 4 <= p1; p += 4) {
        int j0 = __builtin_amdgcn_readlane(jl, 0);
        int j1 = __builtin_amdgcn_readlane(jl, 1);
        int j2 = __builtin_amdgcn_readlane(jl, 2);
        int j3 = __builtin_amdgcn_readlane(jl, 3);
        // prefetch next pass (or tail) indices while this pass computes
        int pn = p + 4 + (lane & 3);
        jl = csr_src[pn < p1 ? pn : (p1 > 0 ? p1 - 1 : 0)];
        float a0 = aarr[j0 * 4 + h], a1 = aarr[j1 * 4 + h];
        float a2 = aarr[j2 * 4 + h], a3 = aarr[j3 * 4 + h];
        float x0[4], x1[4], x2[4], x3[4], s0, s1, s2, s3;
        edge_abs_score(xlr, j0, c4, xr, attv04, x0, s0);
        edge_abs_score(xlr, j1, c4, xr, attv04, x1, s1);
        edge_abs_score(xlr, j2, c4, xr, attv04, x2, s2);
        edge_abs_score(xlr, j3, c4, xr, attv04, x3, s3);
        s0 += a0; s1 += a1; s2 += a2; s3 += a3;
        float sm = fmaxf(fmaxf(s0, s1), fmaxf(s2, s3));
        if (__all(sm <= m + DEFER_THR)) {
            float e0 = __builtin_amdgcn_exp2f(s0 - m);
            float e1 = __builtin_amdgcn_exp2f(s1 - m);
            float e2 = __builtin_amdgcn_exp2f(s2 - m);
            float e3 = __builtin_amdgcn_exp2f(s3 - m);
            l += (e0 + e1) + (e2 + e3);
#pragma unroll
            for (int k = 0; k < 4; ++k)
                acc[k] = fmaf(e0, x0[k], fmaf(e1, x1[k], fmaf(e2, x2[k], fmaf(e3, x3[k], acc[k]))));
        } else {
            float mn = fmaxf(m, sm);
            float corr = __builtin_amdgcn_exp2f(m - mn);
            float e0 = __builtin_amdgcn_exp2f(s0 - mn);
            float e1 = __builtin_amdgcn_exp2f(s1 - mn);
            float e2 = __builtin_amdgcn_exp2f(s2 - mn);
            float e3 = __builtin_amdgcn_exp2f(s3 - mn);
            l = fmaf(l, corr, (e0 + e1) + (e2 + e3));
#pragma unroll
            for (int k = 0; k < 4; ++k)
                acc[k] = fmaf(acc[k], corr,
                         fmaf(e0, x0[k], fmaf(e1, x1[k], fmaf(e2, x2[k], e3 * x3[k]))));
            m = mn;
        }
    }
    // tail 0..3 edges: indices already resident in jl (lanes 0..rem-1)
    int rem = p1 - p;
    for (int tq = 0; tq < rem; ++tq) {
        int j = __builtin_amdgcn_readlane(jl, tq);
        float aj = aarr[j * 4 + h];
        float xa[4], sa;
        edge_abs_score(xlr, j, c4, xr, attv04, xa, sa);
        sa += aj;
        if (__all(sa <= m + DEFER_THR)) {
            float ex = __builtin_amdgcn_exp2f(sa - m);
            l += ex;
#pragma unroll
            for (int k = 0; k < 4; ++k) acc[k] = fmaf(ex, xa[k], acc[k]);
        } else {
            float mn = fmaxf(m, sa);
            float corr = __builtin_amdgcn_exp2f(m - mn);
            float ex = __builtin_amdgcn_exp2f(sa - mn);
            l = fmaf(l, corr, ex);
#pragma unroll
            for (int k = 0; k < 4; ++k) acc[k] = fmaf(acc[k], corr, ex * xa[k]);
            m = mn;
        }
    }

    float inv = 1.f / l;
    f32x4 bv = *reinterpret_cast<const f32x4*>(bias + c4);
    float out[4], s1 = 0.f, s2 = 0.f;
#pragma unroll
    for (int k = 0; k < 4; ++k) {
        out[k] = acc[k] * inv + bv[k];
        s1 += out[k];
        s2 += out[k] * out[k];
    }
    // LN over 256 channels: full-wave butterfly (swizzle xor 1..16, shfl xor 32)
    s1 += SWZF(s1, 0x041F); s2 += SWZF(s2, 0x041F);
    s1 += SWZF(s1, 0x081F); s2 += SWZF(s2, 0x081F);
    s1 += SWZF(s1, 0x101F); s2 += SWZF(s2, 0x101F);
    s1 += SWZF(s1, 0x201F); s2 += SWZF(s2, 0x201F);
    s1 += SWZF(s1, 0x401F); s2 += SWZF(s2, 0x401F);
    s1 += __shfl_xor(s1, 32, 64);
    s2 += __shfl_xor(s2, 32, 64);
    float mu  = s1 * (1.f / 256.f);
    float var = s2 * (1.f / 256.f) - mu * mu;
    float rs  = rsqrtf(var + 1e-5f);
    f32x4 gv  = *reinterpret_cast<const f32x4*>(ln_g + c4);
    f32x4 bbv = *reinterpret_cast<const f32x4*>(ln_b + c4);
    bf16x4 o;
#pragma unroll
    for (int k = 0; k < 4; ++k) {
        float y = (out[k] - mu) * rs * gv[k] + bbv[k];
        y = y > 0.f ? y : expm1f(y);                    // ELU
        o[k] = f2b(y);
    }
    *reinterpret_cast<bf16x4*>(hout + (long)i * 256 + c4) = o;
}

// ---------------- launch ----------------
extern "C" void kernel_launch(void* const* d_in, const int* in_sizes, int n_in,
                              void* d_out, int out_size, void* d_ws, size_t ws_size,
                              hipStream_t stream) {
    const float* x    = (const float*)d_in[0];
    const int*   ei   = (const int*)d_in[1];
    const float* Wl1  = (const float*)d_in[2];
    const float* Wr1  = (const float*)d_in[3];
    const float* att1 = (const float*)d_in[4];
    const float* b1   = (const float*)d_in[5];
    const float* ln1g = (const float*)d_in[6];
    const float* ln1b = (const float*)d_in[7];
    const float* Wl2  = (const float*)d_in[8];
    const float* Wr2  = (const float*)d_in[9];
    const float* att2 = (const float*)d_in[10];
    const float* b2   = (const float*)d_in[11];
    const float* ln2g = (const float*)d_in[12];
    const float* ln2b = (const float*)d_in[13];
    const float* Wmu  = (const float*)d_in[14];
    const float* bmu  = (const float*)d_in[15];
    const float* Wlv  = (const float*)d_in[16];
    const float* blv  = (const float*)d_in[17];

    // workspace layout
    short* bufXL = (short*)d_ws;                       // [N,512] bf16 (xl|xr)
    short* bufH  = bufXL + (long)NN * 512;             // [N,256] bf16 (h)
    short* Wb1t  = bufH + (long)NN * 256;              // 512*256
    short* Wb2t  = Wb1t + 512 * 256;
    short* Wb3t  = Wb2t + 512 * 256;                   // 128*256
    float* bias3 = (float*)(Wb3t + 128 * 256);         // 128
    int* counts  = (int*)(bias3 + 128);
    int* offsets = counts + NN;                        // N+1
    int* cursor  = offsets + NN + 1;
    int* csr_src = cursor + NN;                        // E
    int* blocksum = csr_src + NE;                      // 64
    float* a_arr = (float*)(blocksum + 64);            // [N,4]

    const int* src = ei;
    const int* dst = ei + NE;

    const int NBLK = (NN + 1023) / 1024;               // 49

    // CSR by dst (parallel scan)
    hipMemsetAsync(counts, 0, NN * sizeof(int), stream);
    hist_kernel<<<(NE + 255) / 256, 256, 0, stream>>>(dst, counts);
    scan1_kernel<<<NBLK, 1024, 0, stream>>>(counts, blocksum);
    scan2_kernel<<<1, 64, 0, stream>>>(blocksum, offsets, NBLK);
    scan3_kernel<<<NBLK, 1024, 0, stream>>>(counts, blocksum, offsets, cursor);
    scatter_kernel<<<(NE + 255) / 256, 256, 0, stream>>>(src, dst, cursor, csr_src);

    // pack transposed weights
    pack_w_kernel<<<1153, 256, 0, stream>>>(Wl1, Wr1, Wl2, Wr2, Wmu, Wlv, bmu, blv,
                                            Wb1t, Wb2t, Wb3t, bias3);

    const int GM = (NN + 127) / 128;   // 391
    dim3 g1(GM, 4);                    // Nc=512, 128-col tiles
    dim3 g3(GM, 1);                    // Nc=128

    // layer 1 (A = x in f32, converted in-register)
    gemm_k<1, 0><<<g1, 256, 0, stream>>>(x, Wb1t, bufXL, nullptr, 512);
    att_pre_kernel<<<NN / 4, 256, 0, stream>>>(bufXL, att1, a_arr);
    gat_node_kernel<<<NN / 4, 256, 0, stream>>>(bufXL, a_arr, offsets, csr_src,
                                                att1, b1, ln1g, ln1b, bufH);
    // layer 2
    gemm_k<0, 0><<<g1, 256, 0, stream>>>(bufH, Wb2t, bufXL, nullptr, 512);
    att_pre_kernel<<<NN / 4, 256, 0, stream>>>(bufXL, att2, a_arr);
    gat_node_kernel<<<NN / 4, 256, 0, stream>>>(bufXL, a_arr, offsets, csr_src,
                                                att2, b2, ln2g, ln2b, bufH);
    // heads: [mu|logvar]
    gemm_k<0, 1><<<g3, 256, 0, stream>>>(bufH, Wb3t, d_out, bias3, 128);
}

// Round 12
// 333.609 us; speedup vs baseline: 1.1316x; 1.1211x over previous
//
#include <hip/hip_runtime.h>
#include <hip/hip_bf16.h>

#define NN 50000
#define NE 800000
#define HCn 256
#define LATn 64

typedef short bf16x4 __attribute__((ext_vector_type(4)));
typedef short bf16x8 __attribute__((ext_vector_type(8)));
typedef float f32x4 __attribute__((ext_vector_type(4)));

__device__ __forceinline__ short f2b(float f) {
    __hip_bfloat16 h = __float2bfloat16(f);   // RNE
    return __builtin_bit_cast(short, h);
}
__device__ __forceinline__ float b2f(short s) {
    return __bfloat162float(__builtin_bit_cast(__hip_bfloat16, s));
}

// single-instruction lane swizzle (BitMode xor; works within 32-lane halves).
// DS-pipe op: overlaps with other waves' VALU work (measured r8 vs r10: beats DPP).
#define SWZF(v, pat) __builtin_bit_cast(float, __builtin_amdgcn_ds_swizzle(__builtin_bit_cast(int, v), pat))

#define C04L2E 0.5770780163555854f   // 0.4 * log2(e)
#define C06L2E 0.8656170245333781f   // 0.6 * log2(e)
#define DEFER_THR 8.0f               // defer-max threshold (log2 units)

// ---------------- CSR build ----------------
__global__ void hist_kernel(const int* __restrict__ dst, int* __restrict__ counts) {
    int e = blockIdx.x * 256 + threadIdx.x;
    if (e < NE) atomicAdd(&counts[dst[e]], 1);
}

__global__ __launch_bounds__(1024) void scan1_kernel(int* __restrict__ counts,
                                                     int* __restrict__ blocksum) {
    const int g = blockIdx.x * 1024 + threadIdx.x;
    const int lane = threadIdx.x & 63;
    const int wv = threadIdx.x >> 6;            // 0..15
    int v = (g < NN) ? counts[g] : 0;
    int s = v;
#pragma unroll
    for (int d = 1; d < 64; d <<= 1) {
        int t = __shfl_up(s, d, 64);
        if (lane >= d) s += t;
    }
    __shared__ int wsum[16];
    if (lane == 63) wsum[wv] = s;
    __syncthreads();
    if (threadIdx.x == 0) {
        int run = 0;
#pragma unroll
        for (int q = 0; q < 16; ++q) { int t = wsum[q]; wsum[q] = run; run += t; }
        blocksum[blockIdx.x] = run;
    }
    __syncthreads();
    int excl = s - v + wsum[wv];
    if (g < NN) counts[g] = excl;
}

__global__ void scan2_kernel(int* __restrict__ blocksum, int* __restrict__ offsets, int nblk) {
    const int lane = threadIdx.x;               // 64 threads
    int v = (lane < nblk) ? blocksum[lane] : 0;
    int s = v;
#pragma unroll
    for (int d = 1; d < 64; d <<= 1) {
        int t = __shfl_up(s, d, 64);
        if (lane >= d) s += t;
    }
    if (lane < nblk) blocksum[lane] = s - v;    // exclusive
    if (lane == 0) offsets[NN] = NE;
}

__global__ __launch_bounds__(1024) void scan3_kernel(const int* __restrict__ counts,
                                                     const int* __restrict__ blocksum,
                                                     int* __restrict__ offsets,
                                                     int* __restrict__ cursor) {
    const int g = blockIdx.x * 1024 + threadIdx.x;
    if (g < NN) {
        int v = counts[g] + blocksum[blockIdx.x];
        offsets[g] = v;
        cursor[g]  = v;
    }
}

__global__ void scatter_kernel(const int* __restrict__ src, const int* __restrict__ dst,
                               int* __restrict__ cursor, int* __restrict__ csr_src) {
    int e = blockIdx.x * 256 + threadIdx.x;
    if (e < NE) {
        int p = atomicAdd(&cursor[dst[e]], 1);
        csr_src[p] = src[e];
    }
}

// ---------------- pack weights to bf16, TRANSPOSED: Wbt[n][k] = W[k][n] ----------------
__global__ void pack_w_kernel(const float* __restrict__ Wl1, const float* __restrict__ Wr1,
                              const float* __restrict__ Wl2, const float* __restrict__ Wr2,
                              const float* __restrict__ Wmu, const float* __restrict__ Wlv,
                              const float* __restrict__ bmu, const float* __restrict__ blv,
                              short* __restrict__ Wb1t, short* __restrict__ Wb2t,
                              short* __restrict__ Wb3t, float* __restrict__ bias3) {
    int i = blockIdx.x * 256 + threadIdx.x;
    const int S1 = 512 * 256, S2 = 2 * S1, S3 = S2 + 128 * 256;
    if (i < S1) {
        int c = i >> 8, k = i & 255;
        float v = (c < 256) ? Wl1[k * 256 + c] : Wr1[k * 256 + (c - 256)];
        Wb1t[i] = f2b(v);
    } else if (i < S2) {
        int j = i - S1; int c = j >> 8, k = j & 255;
        float v = (c < 256) ? Wl2[k * 256 + c] : Wr2[k * 256 + (c - 256)];
        Wb2t[j] = f2b(v);
    } else if (i < S3) {
        int j = i - S2; int c = j >> 8, k = j & 255;
        float v = (c < 64) ? Wmu[k * 64 + c] : Wlv[k * 64 + (c - 64)];
        Wb3t[j] = f2b(v);
    } else if (i < S3 + 128) {
        int c = i - S3;
        bias3[c] = (c < 64) ? bmu[c] : blv[c - 64];
    }
}

// ---------------- GEMM: out[M,Nc] = A[M,256] @ W[256,Nc], Wbt[Nc,256] transposed ----------------
// 64-row blocks, NO column grid: A frags loaded once to registers, loop over NCT 64-col
// sub-tiles (32 KB LDS each). ATT=1: fuse a_arr[row][h] = C06L2E * att[h,:]·xl[row,:] for ct<4.
template<int A_F32, int OUT_MODE, int NCT, int ATT>
__global__ __launch_bounds__(256) void gemm_k(
    const void* __restrict__ Ap, const short* __restrict__ Wbt,
    void* __restrict__ outp, const float* __restrict__ bias,
    const float* __restrict__ att, float* __restrict__ a_arr, int Nc)
{
    __shared__ short Bs[64 * 256];   // 32 KB, XOR-swizzled chunks (chunk = 8 shorts = 16B)
    const int t = threadIdx.x;
    const int w = t >> 6, lane = t & 63;
    const int row0 = blockIdx.x * 64;
    const int arow = lane & 15, kq = lane >> 4;
    const int xorc = arow & 7;

    // load A fragments once: row w*16+arow, k-chunks kc*32 + kq*8
    bf16x8 af[8];
    {
        int r0 = row0 + w * 16 + arow; if (r0 > NN - 1) r0 = NN - 1;
        if (A_F32) {
            const float* A = (const float*)Ap;
            const float* base = A + (long)r0 * 256 + kq * 8;
#pragma unroll
            for (int kc = 0; kc < 8; ++kc) {
                const f32x4* q = reinterpret_cast<const f32x4*>(base + kc * 32);
                f32x4 u0 = q[0], u1 = q[1];
#pragma unroll
                for (int j = 0; j < 4; ++j) { af[kc][j] = f2b(u0[j]); af[kc][4 + j] = f2b(u1[j]); }
            }
        } else {
            const short* A = (const short*)Ap;
            const short* base = A + (long)r0 * 256 + kq * 8;
#pragma unroll
            for (int kc = 0; kc < 8; ++kc)
                af[kc] = *reinterpret_cast<const bf16x8*>(base + kc * 32);
        }
    }

    const int sn = t >> 2;           // staging row 0..63
    const int cq = t & 3;            // 4 threads per row

#pragma unroll 1
    for (int ct = 0; ct < NCT; ++ct) {
        // stage B sub-panel: Bs[n][chunk^(n&7)] = Wbt[ct*64+n][chunk]
        {
            const short* wp = Wbt + (long)(ct * 64 + sn) * 256;
            short* bp = &Bs[sn * 256];
            const int sx = sn & 7;
#pragma unroll
            for (int r = 0; r < 8; ++r) {
                int c = cq + r * 4;      // chunk 0..31
                bf16x8 v = *reinterpret_cast<const bf16x8*>(wp + c * 8);
                *reinterpret_cast<bf16x8*>(bp + ((c ^ sx) * 8)) = v;
            }
        }
        __syncthreads();

        f32x4 acc[4];
#pragma unroll
        for (int b = 0; b < 4; ++b) acc[b] = (f32x4){0.f, 0.f, 0.f, 0.f};

#pragma unroll
        for (int kc = 0; kc < 8; ++kc) {
            const int chunk = (kc * 4 + kq) ^ xorc;
#pragma unroll
            for (int nt = 0; nt < 4; ++nt) {
                bf16x8 b = *reinterpret_cast<const bf16x8*>(&Bs[(nt * 16 + arow) * 256 + chunk * 8]);
                acc[nt] = __builtin_amdgcn_mfma_f32_16x16x32_bf16(af[kc], b, acc[nt], 0, 0, 0);
            }
        }

        // fused att_pre: ct<4 covers xl head ct (cols ct*64 .. ct*64+63)
        if (ATT && ct < 4) {
            float av[4];
#pragma unroll
            for (int nt = 0; nt < 4; ++nt) av[nt] = att[ct * 64 + nt * 16 + arow];
#pragma unroll
            for (int r = 0; r < 4; ++r) {
                float pd = av[0] * acc[0][r] + av[1] * acc[1][r]
                         + av[2] * acc[2][r] + av[3] * acc[3][r];
                pd += SWZF(pd, 0x041F);
                pd += SWZF(pd, 0x081F);
                pd += SWZF(pd, 0x101F);
                pd += SWZF(pd, 0x201F);
                int grow = row0 + w * 16 + kq * 4 + r;
                if (arow == 0 && grow < NN) a_arr[grow * 4 + ct] = pd * C06L2E;
            }
        }

        // write out: C/D layout col = arow, row = kq*4 + r
#pragma unroll
        for (int nt = 0; nt < 4; ++nt) {
            int gcol = ct * 64 + nt * 16 + arow;
#pragma unroll
            for (int r = 0; r < 4; ++r) {
                int grow = row0 + w * 16 + kq * 4 + r;
                if (grow < NN) {
                    float v = acc[nt][r];
                    if (OUT_MODE == 0) {
                        ((short*)outp)[(long)grow * Nc + gcol] = f2b(v);
                    } else {
                        v += bias[gcol];
                        float* o = (float*)outp;
                        if (gcol < 64) o[(long)grow * 64 + gcol] = v;
                        else           o[(long)NN * 64 + (long)grow * 64 + (gcol - 64)] = v;
                    }
                }
            }
        }
        __syncthreads();   // Bs reads done before next stage
    }
}

// ---------------- fused GATv2 v2 + index prefetch (ds_swizzle reduce — measured fastest) ----------------
// score (log2 domain, dst-constant term dropped): s = a[j][h] + sum_c (0.4*log2e*att_c)*|xl_jc+xr_ic|
__device__ __forceinline__ void edge_abs_score(const short* __restrict__ xlr, int j, int c4,
                                               const float* xr, const f32x4& attv04,
                                               float* xf, float& s) {
    bf16x4 v = *reinterpret_cast<const bf16x4*>(xlr + (long)j * 512 + c4);
    s = 0.f;
#pragma unroll
    for (int k = 0; k < 4; ++k) {
        xf[k] = b2f(v[k]);
        float vv = xf[k] + xr[k];
        s = fmaf(attv04[k], fabsf(vv), s);   // abs = free input modifier
    }
    // 16-lane head-group reduce: xor 1,2,4,8 (DS pipe, overlaps other waves' VALU)
    s += SWZF(s, 0x041F);
    s += SWZF(s, 0x081F);
    s += SWZF(s, 0x101F);
    s += SWZF(s, 0x201F);
}

__global__ __launch_bounds__(256) void gat_node_kernel(
    const short* __restrict__ xlr, const float* __restrict__ aarr,
    const int* __restrict__ offsets, const int* __restrict__ csr_src,
    const float* __restrict__ att, const float* __restrict__ bias,
    const float* __restrict__ ln_g, const float* __restrict__ ln_b,
    short* __restrict__ hout)
{
    const int i = blockIdx.x * 4 + (threadIdx.x >> 6);
    const int lane = threadIdx.x & 63;
    const int h  = lane >> 4;
    const int c4 = h * 64 + (lane & 15) * 4;   // head*64 + 4 channels

    f32x4 attv04 = *reinterpret_cast<const f32x4*>(att + c4);
#pragma unroll
    for (int k = 0; k < 4; ++k) attv04[k] *= C04L2E;

    float xr[4];
    {
        bf16x4 v = *reinterpret_cast<const bf16x4*>(xlr + (long)i * 512 + 256 + c4);
#pragma unroll
        for (int k = 0; k < 4; ++k) xr[k] = b2f(v[k]);
    }

    const int p0 = offsets[i], p1 = offsets[i + 1];

    // prefetch first pass's indices (clamped, branchless)
    int pp = p0 + (lane & 3);
    int jl = csr_src[pp < NE ? pp : NE - 1];

    float m, l;
    float acc[4];
    // self loop first
    {
        float aj = aarr[i * 4 + h];
        float xf[4], s;
        edge_abs_score(xlr, i, c4, xr, attv04, xf, s);
        m = s + aj; l = 1.f;
#pragma unroll
        for (int k = 0; k < 4; ++k) acc[k] = xf[k];
    }

    int p = p0;
    for (; p + 4 <= p1; p += 4) {
        int j0 = __builtin_amdgcn_readlane(jl, 0);
        int j1 = __builtin_amdgcn_readlane(jl, 1);
        int j2 = __builtin_amdgcn_readlane(jl, 2);
        int j3 = __builtin_amdgcn_readlane(jl, 3);
        // prefetch next pass (or tail) indices while this pass computes
        int pn = p + 4 + (lane & 3);
        jl = csr_src[pn < p1 ? pn : (p1 > 0 ? p1 - 1 : 0)];
        float a0 = aarr[j0 * 4 + h], a1 = aarr[j1 * 4 + h];
        float a2 = aarr[j2 * 4 + h], a3 = aarr[j3 * 4 + h];
        float x0[4], x1[4], x2[4], x3[4], s0, s1, s2, s3;
        edge_abs_score(xlr, j0, c4, xr, attv04, x0, s0);
        edge_abs_score(xlr, j1, c4, xr, attv04, x1, s1);
        edge_abs_score(xlr, j2, c4, xr, attv04, x2, s2);
        edge_abs_score(xlr, j3, c4, xr, attv04, x3, s3);
        s0 += a0; s1 += a1; s2 += a2; s3 += a3;
        float sm = fmaxf(fmaxf(s0, s1), fmaxf(s2, s3));
        if (__all(sm <= m + DEFER_THR)) {
            float e0 = __builtin_amdgcn_exp2f(s0 - m);
            float e1 = __builtin_amdgcn_exp2f(s1 - m);
            float e2 = __builtin_amdgcn_exp2f(s2 - m);
            float e3 = __builtin_amdgcn_exp2f(s3 - m);
            l += (e0 + e1) + (e2 + e3);
#pragma unroll
            for (int k = 0; k < 4; ++k)
                acc[k] = fmaf(e0, x0[k], fmaf(e1, x1[k], fmaf(e2, x2[k], fmaf(e3, x3[k], acc[k]))));
        } else {
            float mn = fmaxf(m, sm);
            float corr = __builtin_amdgcn_exp2f(m - mn);
            float e0 = __builtin_amdgcn_exp2f(s0 - mn);
            float e1 = __builtin_amdgcn_exp2f(s1 - mn);
            float e2 = __builtin_amdgcn_exp2f(s2 - mn);
            float e3 = __builtin_amdgcn_exp2f(s3 - mn);
            l = fmaf(l, corr, (e0 + e1) + (e2 + e3));
#pragma unroll
            for (int k = 0; k < 4; ++k)
                acc[k] = fmaf(acc[k], corr,
                         fmaf(e0, x0[k], fmaf(e1, x1[k], fmaf(e2, x2[k], e3 * x3[k]))));
            m = mn;
        }
    }
    // tail 0..3 edges: indices already resident in jl (lanes 0..rem-1)
    int rem = p1 - p;
    for (int tq = 0; tq < rem; ++tq) {
        int j = __builtin_amdgcn_readlane(jl, tq);
        float aj = aarr[j * 4 + h];
        float xa[4], sa;
        edge_abs_score(xlr, j, c4, xr, attv04, xa, sa);
        sa += aj;
        if (__all(sa <= m + DEFER_THR)) {
            float ex = __builtin_amdgcn_exp2f(sa - m);
            l += ex;
#pragma unroll
            for (int k = 0; k < 4; ++k) acc[k] = fmaf(ex, xa[k], acc[k]);
        } else {
            float mn = fmaxf(m, sa);
            float corr = __builtin_amdgcn_exp2f(m - mn);
            float ex = __builtin_amdgcn_exp2f(sa - mn);
            l = fmaf(l, corr, ex);
#pragma unroll
            for (int k = 0; k < 4; ++k) acc[k] = fmaf(acc[k], corr, ex * xa[k]);
            m = mn;
        }
    }

    float inv = 1.f / l;
    f32x4 bv = *reinterpret_cast<const f32x4*>(bias + c4);
    float out[4], s1 = 0.f, s2 = 0.f;
#pragma unroll
    for (int k = 0; k < 4; ++k) {
        out[k] = acc[k] * inv + bv[k];
        s1 += out[k];
        s2 += out[k] * out[k];
    }
    // LN over 256 channels: full-wave butterfly (swizzle xor 1..16, shfl xor 32)
    s1 += SWZF(s1, 0x041F); s2 += SWZF(s2, 0x041F);
    s1 += SWZF(s1, 0x081F); s2 += SWZF(s2, 0x081F);
    s1 += SWZF(s1, 0x101F); s2 += SWZF(s2, 0x101F);
    s1 += SWZF(s1, 0x201F); s2 += SWZF(s2, 0x201F);
    s1 += SWZF(s1, 0x401F); s2 += SWZF(s2, 0x401F);
    s1 += __shfl_xor(s1, 32, 64);
    s2 += __shfl_xor(s2, 32, 64);
    float mu  = s1 * (1.f / 256.f);
    float var = s2 * (1.f / 256.f) - mu * mu;
    float rs  = rsqrtf(var + 1e-5f);
    f32x4 gv  = *reinterpret_cast<const f32x4*>(ln_g + c4);
    f32x4 bbv = *reinterpret_cast<const f32x4*>(ln_b + c4);
    bf16x4 o;
#pragma unroll
    for (int k = 0; k < 4; ++k) {
        float y = (out[k] - mu) * rs * gv[k] + bbv[k];
        y = y > 0.f ? y : expm1f(y);                    // ELU
        o[k] = f2b(y);
    }
    *reinterpret_cast<bf16x4*>(hout + (long)i * 256 + c4) = o;
}

// ---------------- launch ----------------
extern "C" void kernel_launch(void* const* d_in, const int* in_sizes, int n_in,
                              void* d_out, int out_size, void* d_ws, size_t ws_size,
                              hipStream_t stream) {
    const float* x    = (const float*)d_in[0];
    const int*   ei   = (const int*)d_in[1];
    const float* Wl1  = (const float*)d_in[2];
    const float* Wr1  = (const float*)d_in[3];
    const float* att1 = (const float*)d_in[4];
    const float* b1   = (const float*)d_in[5];
    const float* ln1g = (const float*)d_in[6];
    const float* ln1b = (const float*)d_in[7];
    const float* Wl2  = (const float*)d_in[8];
    const float* Wr2  = (const float*)d_in[9];
    const float* att2 = (const float*)d_in[10];
    const float* b2   = (const float*)d_in[11];
    const float* ln2g = (const float*)d_in[12];
    const float* ln2b = (const float*)d_in[13];
    const float* Wmu  = (const float*)d_in[14];
    const float* bmu  = (const float*)d_in[15];
    const float* Wlv  = (const float*)d_in[16];
    const float* blv  = (const float*)d_in[17];

    // workspace layout
    short* bufXL = (short*)d_ws;                       // [N,512] bf16 (xl|xr)
    short* bufH  = bufXL + (long)NN * 512;             // [N,256] bf16 (h)
    short* Wb1t  = bufH + (long)NN * 256;              // 512*256
    short* Wb2t  = Wb1t + 512 * 256;
    short* Wb3t  = Wb2t + 512 * 256;                   // 128*256
    float* bias3 = (float*)(Wb3t + 128 * 256);         // 128
    int* counts  = (int*)(bias3 + 128);
    int* offsets = counts + NN;                        // N+1
    int* cursor  = offsets + NN + 1;
    int* csr_src = cursor + NN;                        // E
    int* blocksum = csr_src + NE;                      // 64
    float* a_arr = (float*)(blocksum + 64);            // [N,4]

    const int* src = ei;
    const int* dst = ei + NE;

    const int NBLK = (NN + 1023) / 1024;               // 49

    // CSR by dst (parallel scan)
    hipMemsetAsync(counts, 0, NN * sizeof(int), stream);
    hist_kernel<<<(NE + 255) / 256, 256, 0, stream>>>(dst, counts);
    scan1_kernel<<<NBLK, 1024, 0, stream>>>(counts, blocksum);
    scan2_kernel<<<1, 64, 0, stream>>>(blocksum, offsets, NBLK);
    scan3_kernel<<<NBLK, 1024, 0, stream>>>(counts, blocksum, offsets, cursor);
    scatter_kernel<<<(NE + 255) / 256, 256, 0, stream>>>(src, dst, cursor, csr_src);

    // pack transposed weights
    pack_w_kernel<<<1153, 256, 0, stream>>>(Wl1, Wr1, Wl2, Wr2, Wmu, Wlv, bmu, blv,
                                            Wb1t, Wb2t, Wb3t, bias3);

    const int GM = (NN + 63) / 64;     // 782 row-blocks

    // layer 1 (A = x in f32, converted in-register; att_pre fused)
    gemm_k<1, 0, 8, 1><<<GM, 256, 0, stream>>>(x, Wb1t, bufXL, nullptr, att1, a_arr, 512);
    gat_node_kernel<<<NN / 4, 256, 0, stream>>>(bufXL, a_arr, offsets, csr_src,
                                                att1, b1, ln1g, ln1b, bufH);
    // layer 2
    gemm_k<0, 0, 8, 1><<<GM, 256, 0, stream>>>(bufH, Wb2t, bufXL, nullptr, att2, a_arr, 512);
    gat_node_kernel<<<NN / 4, 256, 0, stream>>>(bufXL, a_arr, offsets, csr_src,
                                                att2, b2, ln2g, ln2b, bufH);
    // heads: [mu|logvar]
    gemm_k<0, 1, 2, 0><<<GM, 256, 0, stream>>>(bufH, Wb3t, d_out, bias3, nullptr, nullptr, 128);
}